// Round 9
// baseline (2428.135 us; speedup 1.0000x reference)
//
#include <hip/hip_runtime.h>
#include <math.h>

// Problem constants
#define BB 256   // batch
#define TT 128   // seq len
#define DD 256   // input dim
#define HH 512   // hidden (LSTM 1/2); LSTM 3 hidden = 2*HH = 1024

typedef __bf16 bf16x8 __attribute__((ext_vector_type(8)));
typedef float  f32x4  __attribute__((ext_vector_type(4)));

__device__ inline unsigned short f2bf(float f) {
  unsigned u = __builtin_bit_cast(unsigned, f);
  unsigned r = (u + 0x7fffu + ((u >> 16) & 1u)) >> 16;  // RNE
  return (unsigned short)r;
}
__device__ inline float bf2f(unsigned short h) {
  unsigned u = ((unsigned)h) << 16;
  return __builtin_bit_cast(float, u);
}
__device__ inline float sigm(float x)   { return 1.f / (1.f + __expf(-x)); }
__device__ inline float tanh_f(float x) { return 2.f / (1.f + __expf(-2.f * x)) - 1.f; }

// async global->LDS, 16 bytes per lane. lds ptr must be wave-uniform;
// HW writes at lds + lane*16 (guide §5). Global ptr is per-lane.
__device__ __forceinline__ void gl16(const void* g, void* l) {
  __builtin_amdgcn_global_load_lds(
      (const __attribute__((address_space(1))) unsigned int*)g,
      (__attribute__((address_space(3))) unsigned int*)l, 16, 0, 0);
}

// counted waits on the wave's own outstanding global_load_lds ops
__device__ __forceinline__ void vmw12() { asm volatile("s_waitcnt vmcnt(12)" ::: "memory"); }
__device__ __forceinline__ void vmw8()  { asm volatile("s_waitcnt vmcnt(8)"  ::: "memory"); }
__device__ __forceinline__ void vmw4()  { asm volatile("s_waitcnt vmcnt(4)"  ::: "memory"); }
__device__ __forceinline__ void vmw0()  { asm volatile("s_waitcnt vmcnt(0)"  ::: "memory"); }

// ---------------------------------------------------------------------------
// Prep: convert/pack everything to bf16, gate-interleaved weight layout.
// Packed weight row n = j*4 + g  (g: 0=i,1=f,2=g,3=o), K = [ih | hh] concat.
// xb transposed to [T][B][D] so a step's A-tile is contiguous.
// Zeroes comb slot 0, hs slots, and all c states (ws is poisoned each call).
// ---------------------------------------------------------------------------
__global__ void prep(const float* __restrict__ x,
                     const float* __restrict__ Wf_ih, const float* __restrict__ Wf_hh, const float* __restrict__ bf_,
                     const float* __restrict__ Wb_ih, const float* __restrict__ Wb_hh, const float* __restrict__ bb_,
                     const float* __restrict__ Ws_ih, const float* __restrict__ Ws_hh, const float* __restrict__ bs_,
                     unsigned short* __restrict__ xb, unsigned short* __restrict__ Wpf,
                     unsigned short* __restrict__ Wpb, unsigned short* __restrict__ Wps,
                     float* __restrict__ bpf, float* __restrict__ bpb, float* __restrict__ bps,
                     unsigned short* __restrict__ comb, unsigned short* __restrict__ hs,
                     float* __restrict__ cf, float* __restrict__ cb, float* __restrict__ cs) {
  const long gid = (long)blockIdx.x * blockDim.x + threadIdx.x;
  const long stride = (long)gridDim.x * blockDim.x;

  // x [B][T][D] -> xb [T][B][D] (bf16)
  for (long i = gid; i < (long)BB * TT * DD; i += stride) {
    long k = i % DD;
    long bt = i / DD;
    long t = bt % TT;
    long b = bt / TT;
    xb[(t * BB + b) * DD + k] = f2bf(x[i]);
  }
  // fwd/bwd packed weights: [2048][768]
  for (long i = gid; i < 2048L * 768; i += stride) {
    int n = (int)(i / 768), k = (int)(i - (long)n * 768);
    int j = n >> 2, g = n & 3;
    float vf = (k < DD) ? Wf_ih[(size_t)(g * HH + j) * DD + k]
                        : Wf_hh[(size_t)(g * HH + j) * HH + (k - DD)];
    float vb = (k < DD) ? Wb_ih[(size_t)(g * HH + j) * DD + k]
                        : Wb_hh[(size_t)(g * HH + j) * HH + (k - DD)];
    Wpf[i] = f2bf(vf);
    Wpb[i] = f2bf(vb);
  }
  // layer-3 packed weights: [4096][2048]
  for (long i = gid; i < 4096L * 2048; i += stride) {
    int n = (int)(i >> 11), k = (int)(i & 2047);
    int j = n >> 2, g = n & 3;
    float v = (k < 1024) ? Ws_ih[(size_t)(g * 1024 + j) * 1024 + k]
                         : Ws_hh[(size_t)(g * 1024 + j) * 1024 + (k - 1024)];
    Wps[i] = f2bf(v);
  }
  // biases (fp32, gate-interleaved)
  for (long i = gid; i < 2048; i += stride) {
    int j = (int)(i >> 2), g = (int)(i & 3);
    bpf[i] = bf_[g * HH + j];
    bpb[i] = bb_[g * HH + j];
  }
  for (long i = gid; i < 4096; i += stride) {
    int j = (int)(i >> 2), g = (int)(i & 3);
    bps[i] = bs_[g * 1024 + j];
  }
  // zero init: comb slot 0 (h_{-1} = 0), hs (both slots), c states
  for (long i = gid; i < (long)BB * 1024; i += stride) comb[i] = 0;
  for (long i = gid; i < 2L * BB * 1024; i += stride) hs[i] = 0;
  for (long i = gid; i < (long)BB * HH; i += stride) { cf[i] = 0.f; cb[i] = 0.f; }
  for (long i = gid; i < (long)BB * 1024; i += stride) cs[i] = 0.f;
}

// ---------------------------------------------------------------------------
// 64x64-tile GEMM, global_load_lds 5-buffer pipeline, BK=64, depth-4 in
// flight, ONE barrier per K-step (R8 post-mortem: R6/R7 were convoy-bound
// at depth 3 + 2 barriers/step; deepen the pipe, halve the barriers).
//
// Per K-step ks:  vmcnt(4*min(3,NKS-1-ks))   (tile ks landed; up to 3 more
//                                             tiles stay in flight)
//                 s_barrier                   (all waves: tile ks complete,
//                                             and all waves done step ks-1)
//                 stage(ks+4) -> buf (ks+4)%5 == (ks-1)%5  (WAR-safe: that
//                                             buf was last read in step ks-1)
//                 ds_read + MFMA on buf ks%5
// Trailing s_barrier protects the epilogue scratch overlap.
//
// LDS per buffer: A tile [64 rows][64 k] bf16 (8 KB) then B tile [64][64]
// (8 KB); 5 buffers = 80 KB; 2 blocks/CU = 160 KB. Row stride 128 B.
// XOR swizzle: LDS byte (row*128 + e) holds global k-byte (e ^ ((row&7)<<4))
// — applied on the SOURCE address at staging and on the ds_read address.
//
// A rows from aseg0 (k < KSPLIT) then aseg1 (k >= KSPLIT), 64-aligned.
// Frag: A[m=lane&15][k=(lane>>4)*8+j]; B likewise; C/D col=lane&15,
// row=(lane>>4)*4+reg.
// ---------------------------------------------------------------------------
template<int NKS, int KSPLIT>
__device__ __forceinline__ void gemm_tile_lds(
    const unsigned short* __restrict__ a0, long as0,   // A segment 0 (at row m0)
    const unsigned short* __restrict__ a1, long as1,   // A segment 1
    const unsigned short* __restrict__ wb, long ws,    // weight rows (at col n0)
    char* sm, int tid, f32x4 (&acc)[4]) {
  const int rl   = tid >> 3;              // staging row within 32-row half
  const int eb   = (tid & 7) * 16;        // staging byte-in-row
  const int kel  = (eb ^ ((rl & 7) << 4)) >> 1;   // pre-swizzled element offset
  const int wuni = (tid >> 6) * 1024;     // wave-uniform LDS sub-base

  const int lane = tid & 63;
  const int w    = tid >> 6;
  const int ln   = lane & 15;
  const int q    = lane >> 4;
  const int swzr = (ln & 7) << 4;
  const int col  = w * 16 + ln;

  auto stage = [&](int buf, int k0) {
    char* lA = sm + buf * 16384;
    char* lB = lA + 8192;
    const unsigned short* ab = (k0 < KSPLIT) ? (a0 + k0) : (a1 + (k0 - KSPLIT));
    const long astr = (k0 < KSPLIT) ? as0 : as1;
#pragma unroll
    for (int h = 0; h < 2; ++h) {
      const int row = h * 32 + rl;
      gl16(ab + (long)row * astr + kel, lA + h * 4096 + wuni);
      gl16(wb + (long)row * ws + k0 + kel, lB + h * 4096 + wuni);
    }
  };

  // prologue: 4 tiles in flight (NKS >= 12 always here)
  stage(0, 0); stage(1, 64); stage(2, 128); stage(3, 192);

  for (int ks = 0; ks < NKS; ++ks) {
    if (ks < NKS - 3)       vmw12();  // tile ks landed; 3 tiles still in flight
    else if (ks == NKS - 3) vmw8();
    else if (ks == NKS - 2) vmw4();
    else                    vmw0();
    __builtin_amdgcn_sched_barrier(0);
    __builtin_amdgcn_s_barrier();               // tile ks ready; step ks-1 fully read
    __builtin_amdgcn_sched_barrier(0);
    if (ks + 4 < NKS) stage((ks + 4) % 5, (ks + 4) * 64);  // overwrites buf (ks-1)%5
    const char* lA = sm + (ks % 5) * 16384;
    const char* lB = lA + 8192;
#pragma unroll
    for (int ks2 = 0; ks2 < 2; ++ks2) {
      const int eo = (ks2 * 64 + q * 16) ^ swzr;
      const bf16x8 bf = *reinterpret_cast<const bf16x8*>(lB + col * 128 + eo);
#pragma unroll
      for (int mb = 0; mb < 4; ++mb) {
        const bf16x8 af = *reinterpret_cast<const bf16x8*>(lA + (mb * 16 + ln) * 128 + eo);
        acc[mb] = __builtin_amdgcn_mfma_f32_16x16x32_bf16(af, bf, acc[mb], 0, 0, 0);
      }
    }
    __builtin_amdgcn_sched_barrier(0);
  }
  __builtin_amdgcn_s_barrier();   // all waves done with last buffer (epilogue reuses sm)
  // exits with vm outstanding = 0.
}

// ---------------------------------------------------------------------------
// Fused phase p (p = 0..128), two independent concurrent sub-kernels
// (R6 winning schedule: merged K=2048 s3, no Gs partials):
//   blocks   0..255: fb(t=p)   — layer1/2 fwd+bwd step, K=768, writes comb[t+1]
//   blocks 256..511: s3(s=p-1) — FULL K=2048 layer-3 step (comb_s | h_{s-1})
//                                @ Wps^T + cell update -> hs[(s+1)&1]
// s3(s) inputs: comb slot s+1=p (fb phase p-1), hs slot s&1 (s3 phase p-1).
// XCD-pinned n-panels (bi&7 = XCD) dedup weight fetches within a phase.
// ---------------------------------------------------------------------------
__global__ __launch_bounds__(256, 2) void phase(int p,
    const unsigned short* __restrict__ xb,
    const unsigned short* __restrict__ Wpf, const unsigned short* __restrict__ Wpb,
    const float* __restrict__ bpf, const float* __restrict__ bpb,
    unsigned short* __restrict__ comb, float* __restrict__ cf, float* __restrict__ cb,
    const unsigned short* __restrict__ Wps, const float* __restrict__ bps,
    unsigned short* __restrict__ hs, float* __restrict__ cs) {
  __shared__ __align__(16) char sm[81920];
  const int bi = blockIdx.x;
  const int tid = threadIdx.x;
  const int w = tid >> 6;
  const int lane = tid & 63;
  const int q = lane >> 4;
  const int ln = lane & 15;
  const int col = w * 16 + ln;
  float* scratch = (float*)sm;   // 64x68 f32 epilogue scratch (17.4 KB), reused after K-loop

  if (bi < 256) {
    // ---------------- layer 1/2 step, t = p ----------------
    const int t = p;
    if (t >= TT) return;
    const int xcd = bi & 7;
    const int idx = bi >> 3;          // 0..31
    const int m0 = (idx & 3) * 64;
    const int slot = idx >> 2;        // 0..7
    const int panel = xcd * 8 + slot; // 0..63
    const int dir = panel & 1;
    const int n0 = (panel >> 1) * 64;
    const unsigned short* __restrict__ W = dir ? Wpb : Wpf;
    const float* __restrict__ bias = dir ? bpb : bpf;
    float* __restrict__ cbuf = dir ? cb : cf;
    const int dofs = dir ? HH : 0;
    const int tx = dir ? (TT - 1 - t) : t;

    f32x4 acc[4];
#pragma unroll
    for (int mb = 0; mb < 4; ++mb) acc[mb] = (f32x4){0.f, 0.f, 0.f, 0.f};
    gemm_tile_lds<768 / 64, DD>(
        xb + ((long)tx * BB + m0) * DD, DD,
        comb + ((long)t * BB + m0) * 1024 + dofs, 1024,
        W + (long)n0 * 768, 768, sm, tid, acc);

#pragma unroll
    for (int mb = 0; mb < 4; ++mb)
#pragma unroll
      for (int r = 0; r < 4; ++r)
        scratch[(mb * 16 + q * 4 + r) * 68 + col] = acc[mb][r];
    __syncthreads();

#pragma unroll
    for (int r = 0; r < 4; ++r) {
      const int cid = tid + r * 256;
      const int bl = cid >> 4;           // 0..63
      const int jl = cid & 15;           // 0..15
      const int b = m0 + bl;
      const int j = (n0 >> 2) + jl;      // 0..511
      const f32x4 g  = *reinterpret_cast<const f32x4*>(&scratch[bl * 68 + jl * 4]);
      const f32x4 bv = *reinterpret_cast<const f32x4*>(&bias[n0 + jl * 4]);
      const float gi = g[0] + bv[0];
      const float gf = g[1] + bv[1];
      const float gg = g[2] + bv[2];
      const float go = g[3] + bv[3];
      const float c_old = cbuf[(size_t)b * HH + j];
      const float c_new = sigm(gf) * c_old + sigm(gi) * tanh_f(gg);
      const float h = sigm(go) * tanh_f(c_new);
      cbuf[(size_t)b * HH + j] = c_new;
      comb[((size_t)(t + 1) * BB + b) * 1024 + dofs + j] = f2bf(h);
    }
  } else {
    // ---------------- layer 3 full step, s = p-1 ----------------
    if (p < 1) return;
    const int s = p - 1;
    const int bb2 = bi - 256;
    const int xcd = bb2 & 7;
    const int idx = bb2 >> 3;                     // 0..31
    const int m0 = (idx & 3) * 64;
    const int n0 = (xcd * 8 + (idx >> 2)) * 64;   // pinned panel 0..63 -> n0 0..4032

    f32x4 acc[4];
#pragma unroll
    for (int mb = 0; mb < 4; ++mb) acc[mb] = (f32x4){0.f, 0.f, 0.f, 0.f};
    gemm_tile_lds<2048 / 64, 1024>(
        comb + ((long)p * BB + m0) * 1024, 1024,          // combined[s] = slot p
        hs + ((long)(s & 1) * BB + m0) * 1024, 1024,      // h_{s-1}
        Wps + (long)n0 * 2048, 2048, sm, tid, acc);

#pragma unroll
    for (int mb = 0; mb < 4; ++mb)
#pragma unroll
      for (int r = 0; r < 4; ++r)
        scratch[(mb * 16 + q * 4 + r) * 68 + col] = acc[mb][r];
    __syncthreads();

#pragma unroll
    for (int r = 0; r < 4; ++r) {
      const int cid = tid + r * 256;
      const int bl = cid >> 4;
      const int jl = cid & 15;
      const int b = m0 + bl;
      const int j = (n0 >> 2) + jl;      // 0..1023
      const f32x4 g  = *reinterpret_cast<const f32x4*>(&scratch[bl * 68 + jl * 4]);
      const f32x4 bv = *reinterpret_cast<const f32x4*>(&bps[n0 + jl * 4]);
      const float gi = g[0] + bv[0];
      const float gf = g[1] + bv[1];
      const float gg = g[2] + bv[2];
      const float go = g[3] + bv[3];
      const float c_old = cs[(size_t)b * 1024 + j];
      const float c_new = sigm(gf) * c_old + sigm(gi) * tanh_f(gg);
      const float h = sigm(go) * tanh_f(c_new);
      cs[(size_t)b * 1024 + j] = c_new;
      hs[((size_t)((s + 1) & 1) * BB + b) * 1024 + j] = f2bf(h);
    }
  }
}

// ---------------------------------------------------------------------------
// out[b][l] = sigmoid(h_final[b] . Wl[l] + bl[l]);  h_final = hs slot (T&1)=0
// ---------------------------------------------------------------------------
__global__ __launch_bounds__(256) void classifier(const unsigned short* __restrict__ hs,
                                                  const float* __restrict__ Wl,
                                                  const float* __restrict__ bl,
                                                  float* __restrict__ out) {
  const int b = blockIdx.x;
  const int tid = threadIdx.x;
  const unsigned short* hb = hs + (size_t)b * 1024;  // slot 0 (T even)
  float s0 = 0.f, s1 = 0.f;
#pragma unroll
  for (int kk = 0; kk < 4; ++kk) {
    const int k = tid * 4 + kk;
    const float hv = bf2f(hb[k]);
    s0 += hv * Wl[k];
    s1 += hv * Wl[1024 + k];
  }
  for (int off = 32; off > 0; off >>= 1) {
    s0 += __shfl_down(s0, off);
    s1 += __shfl_down(s1, off);
  }
  __shared__ float red[8];
  const int w = tid >> 6;
  if ((tid & 63) == 0) { red[w * 2] = s0; red[w * 2 + 1] = s1; }
  __syncthreads();
  if (tid == 0) {
    const float l0 = red[0] + red[2] + red[4] + red[6] + bl[0];
    const float l1 = red[1] + red[3] + red[5] + red[7] + bl[1];
    out[b * 2 + 0] = sigm(l0);
    out[b * 2 + 1] = sigm(l1);
  }
}

// ---------------------------------------------------------------------------
extern "C" void kernel_launch(void* const* d_in, const int* in_sizes, int n_in,
                              void* d_out, int out_size, void* d_ws, size_t ws_size,
                              hipStream_t stream) {
  const float* x     = (const float*)d_in[0];
  const float* Wf_ih = (const float*)d_in[1];
  const float* Wf_hh = (const float*)d_in[2];
  const float* bf_   = (const float*)d_in[3];
  const float* Wb_ih = (const float*)d_in[4];
  const float* Wb_hh = (const float*)d_in[5];
  const float* bb_   = (const float*)d_in[6];
  const float* Ws_ih = (const float*)d_in[7];
  const float* Ws_hh = (const float*)d_in[8];
  const float* bs_   = (const float*)d_in[9];
  const float* Wl    = (const float*)d_in[10];
  const float* bl    = (const float*)d_in[11];
  float* out = (float*)d_out;

  char* ws = (char*)d_ws;
  size_t off = 0;
  auto take = [&](size_t bytes) -> void* {
    void* p = ws + off;
    off += (bytes + 255) & ~(size_t)255;
    return p;
  };
  unsigned short* xb   = (unsigned short*)take((size_t)BB * TT * DD * 2);       // 16 MB
  unsigned short* Wpf  = (unsigned short*)take((size_t)2048 * 768 * 2);         // 3 MB
  unsigned short* Wpb  = (unsigned short*)take((size_t)2048 * 768 * 2);         // 3 MB
  unsigned short* Wps  = (unsigned short*)take((size_t)4096 * 2048 * 2);        // 16 MB
  float* bpf = (float*)take(2048 * 4);
  float* bpb = (float*)take(2048 * 4);
  float* bps = (float*)take(4096 * 4);
  unsigned short* comb = (unsigned short*)take((size_t)(TT + 1) * BB * 1024 * 2); // 67.6 MB
  unsigned short* hs   = (unsigned short*)take((size_t)2 * BB * 1024 * 2);      // 1 MB
  float* cf = (float*)take((size_t)BB * HH * 4);
  float* cb = (float*)take((size_t)BB * HH * 4);
  float* cs = (float*)take((size_t)BB * 1024 * 4);
  // total ~111 MB

  prep<<<2048, 256, 0, stream>>>(x, Wf_ih, Wf_hh, bf_, Wb_ih, Wb_hh, bb_,
                                 Ws_ih, Ws_hh, bs_, xb, Wpf, Wpb, Wps,
                                 bpf, bpb, bps, comb, hs, cf, cb, cs);
  for (int p = 0; p <= TT; ++p)
    phase<<<512, 256, 0, stream>>>(p, xb, Wpf, Wpb, bpf, bpb, comb, cf, cb,
                                   Wps, bps, hs, cs);
  classifier<<<256, 256, 0, stream>>>(hs, Wl, bl, out);
}

// Round 11
// 1966.078 us; speedup vs baseline: 1.2350x; 1.2350x over previous
//
#include <hip/hip_runtime.h>
#include <math.h>

// Problem constants
#define BB 256   // batch
#define TT 128   // seq len
#define DD 256   // input dim
#define HH 512   // hidden (LSTM 1/2); LSTM 3 hidden = 2*HH = 1024

typedef __bf16 bf16x8 __attribute__((ext_vector_type(8)));
typedef float  f32x4  __attribute__((ext_vector_type(4)));

__device__ inline unsigned short f2bf(float f) {
  unsigned u = __builtin_bit_cast(unsigned, f);
  unsigned r = (u + 0x7fffu + ((u >> 16) & 1u)) >> 16;  // RNE
  return (unsigned short)r;
}
__device__ inline float bf2f(unsigned short h) {
  unsigned u = ((unsigned)h) << 16;
  return __builtin_bit_cast(float, u);
}
__device__ inline float sigm(float x)   { return 1.f / (1.f + __expf(-x)); }
__device__ inline float tanh_f(float x) { return 2.f / (1.f + __expf(-2.f * x)) - 1.f; }

// async global->LDS, 16 bytes per lane. lds ptr must be wave-uniform;
// HW writes at lds + lane*16 (guide §5). Global ptr is per-lane.
__device__ __forceinline__ void gl16(const void* g, void* l) {
  __builtin_amdgcn_global_load_lds(
      (const __attribute__((address_space(1))) unsigned int*)g,
      (__attribute__((address_space(3))) unsigned int*)l, 16, 0, 0);
}

// counted waits on the wave's own outstanding global_load_lds ops
__device__ __forceinline__ void vmw8() { asm volatile("s_waitcnt vmcnt(8)" ::: "memory"); }
__device__ __forceinline__ void vmw4() { asm volatile("s_waitcnt vmcnt(4)" ::: "memory"); }
__device__ __forceinline__ void vmw0() { asm volatile("s_waitcnt vmcnt(0)" ::: "memory"); }

// ---------------------------------------------------------------------------
// Prep: convert/pack everything to bf16, gate-interleaved weight layout.
// Packed weight row n = j*4 + g  (g: 0=i,1=f,2=g,3=o), K = [ih | hh] concat.
// xb transposed to [T][B][D] so a step's A-tile is contiguous.
// Zeroes comb slot 0, hs slots, and all c states (ws is poisoned each call).
// ---------------------------------------------------------------------------
__global__ void prep(const float* __restrict__ x,
                     const float* __restrict__ Wf_ih, const float* __restrict__ Wf_hh, const float* __restrict__ bf_,
                     const float* __restrict__ Wb_ih, const float* __restrict__ Wb_hh, const float* __restrict__ bb_,
                     const float* __restrict__ Ws_ih, const float* __restrict__ Ws_hh, const float* __restrict__ bs_,
                     unsigned short* __restrict__ xb, unsigned short* __restrict__ Wpf,
                     unsigned short* __restrict__ Wpb, unsigned short* __restrict__ Wps,
                     float* __restrict__ bpf, float* __restrict__ bpb, float* __restrict__ bps,
                     unsigned short* __restrict__ comb, unsigned short* __restrict__ hs,
                     float* __restrict__ cf, float* __restrict__ cb, float* __restrict__ cs) {
  const long gid = (long)blockIdx.x * blockDim.x + threadIdx.x;
  const long stride = (long)gridDim.x * blockDim.x;

  // x [B][T][D] -> xb [T][B][D] (bf16)
  for (long i = gid; i < (long)BB * TT * DD; i += stride) {
    long k = i % DD;
    long bt = i / DD;
    long t = bt % TT;
    long b = bt / TT;
    xb[(t * BB + b) * DD + k] = f2bf(x[i]);
  }
  // fwd/bwd packed weights: [2048][768]
  for (long i = gid; i < 2048L * 768; i += stride) {
    int n = (int)(i / 768), k = (int)(i - (long)n * 768);
    int j = n >> 2, g = n & 3;
    float vf = (k < DD) ? Wf_ih[(size_t)(g * HH + j) * DD + k]
                        : Wf_hh[(size_t)(g * HH + j) * HH + (k - DD)];
    float vb = (k < DD) ? Wb_ih[(size_t)(g * HH + j) * DD + k]
                        : Wb_hh[(size_t)(g * HH + j) * HH + (k - DD)];
    Wpf[i] = f2bf(vf);
    Wpb[i] = f2bf(vb);
  }
  // layer-3 packed weights: [4096][2048]
  for (long i = gid; i < 4096L * 2048; i += stride) {
    int n = (int)(i >> 11), k = (int)(i & 2047);
    int j = n >> 2, g = n & 3;
    float v = (k < 1024) ? Ws_ih[(size_t)(g * 1024 + j) * 1024 + k]
                         : Ws_hh[(size_t)(g * 1024 + j) * 1024 + (k - 1024)];
    Wps[i] = f2bf(v);
  }
  // biases (fp32, gate-interleaved)
  for (long i = gid; i < 2048; i += stride) {
    int j = (int)(i >> 2), g = (int)(i & 3);
    bpf[i] = bf_[g * HH + j];
    bpb[i] = bb_[g * HH + j];
  }
  for (long i = gid; i < 4096; i += stride) {
    int j = (int)(i >> 2), g = (int)(i & 3);
    bps[i] = bs_[g * 1024 + j];
  }
  // zero init: comb slot 0 (h_{-1} = 0), hs (both slots), c states
  for (long i = gid; i < (long)BB * 1024; i += stride) comb[i] = 0;
  for (long i = gid; i < 2L * BB * 1024; i += stride) hs[i] = 0;
  for (long i = gid; i < (long)BB * HH; i += stride) { cf[i] = 0.f; cb[i] = 0.f; }
  for (long i = gid; i < (long)BB * 1024; i += stride) cs[i] = 0.f;
}

// ---------------------------------------------------------------------------
// 64x64-tile GEMM, global_load_lds 4-buffer pipeline, BK=64, depth-3 in
// flight, ONE barrier per K-step.
// (R10 post-mortem: R9 proved this loop skeleton correct AND ~30% faster
// per step; its regression was the 80KB-LDS occupancy cliff. 4 buffers =
// 64 KB restores 2 blocks/CU.)
//
// Per K-step ks:  vmcnt(4*min(2,NKS-1-ks))  (tile ks landed; up to 2 more
//                                            tiles stay in flight)
//                 s_barrier                  (all waves: tile ks visible AND
//                                            all waves done reading step ks-1)
//                 stage(ks+3) -> buf (ks+3)&3 == (ks-1)&3   (WAR-safe)
//                 setprio(1); ds_read + MFMA on buf ks&3; setprio(0)
//
// LDS per buffer: A tile [64 rows][64 k] bf16 (8 KB) then B tile [64][64]
// (8 KB); 4 buffers = 64 KB. Row stride 128 B. XOR swizzle: LDS byte
// (row*128 + e) holds global k-byte (e ^ ((row&7)<<4)) — applied on the
// SOURCE address at staging (gload_lds writes linearly) and on the ds_read.
//
// Epilogue scratch (17.4 KB = bufs 0-1 region) is safe: the last two steps
// read bufs 2,3 for both NKS=12 and NKS=32, and the step-(NKS-1) barrier
// proves all earlier-buffer reads complete before any wave exits the loop.
//
// A rows from aseg0 (k < KSPLIT) then aseg1 (k >= KSPLIT), 64-aligned.
// Frag: A[m=lane&15][k=(lane>>4)*8+j]; B likewise; C/D col=lane&15,
// row=(lane>>4)*4+reg.
// ---------------------------------------------------------------------------
template<int NKS, int KSPLIT>
__device__ __forceinline__ void gemm_tile_lds(
    const unsigned short* __restrict__ a0, long as0,   // A segment 0 (at row m0)
    const unsigned short* __restrict__ a1, long as1,   // A segment 1
    const unsigned short* __restrict__ wb, long ws,    // weight rows (at col n0)
    char* sm, int tid, f32x4 (&acc)[4]) {
  const int rl   = tid >> 3;              // staging row within 32-row half
  const int eb   = (tid & 7) * 16;        // staging byte-in-row
  const int kel  = (eb ^ ((rl & 7) << 4)) >> 1;   // pre-swizzled element offset
  const int wuni = (tid >> 6) * 1024;     // wave-uniform LDS sub-base

  const int lane = tid & 63;
  const int w    = tid >> 6;
  const int ln   = lane & 15;
  const int q    = lane >> 4;
  const int swzr = (ln & 7) << 4;
  const int col  = w * 16 + ln;

  auto stage = [&](int buf, int k0) {
    char* lA = sm + buf * 16384;
    char* lB = lA + 8192;
    const unsigned short* ab = (k0 < KSPLIT) ? (a0 + k0) : (a1 + (k0 - KSPLIT));
    const long astr = (k0 < KSPLIT) ? as0 : as1;
#pragma unroll
    for (int h = 0; h < 2; ++h) {
      const int row = h * 32 + rl;
      gl16(ab + (long)row * astr + kel, lA + h * 4096 + wuni);
      gl16(wb + (long)row * ws + k0 + kel, lB + h * 4096 + wuni);
    }
  };

  // prologue: 3 tiles in flight (NKS >= 12 always here)
  stage(0, 0); stage(1, 64); stage(2, 128);

#pragma unroll 4
  for (int ks = 0; ks < NKS; ++ks) {
    if (ks < NKS - 2)       vmw8();   // tile ks landed; 2 tiles still in flight
    else if (ks == NKS - 2) vmw4();
    else                    vmw0();
    __builtin_amdgcn_sched_barrier(0);
    __builtin_amdgcn_s_barrier();               // tile ks ready; step ks-1 fully read
    __builtin_amdgcn_sched_barrier(0);
    if (ks + 3 < NKS) stage((ks + 3) & 3, (ks + 3) * 64);  // overwrites buf (ks-1)&3
    const char* lA = sm + (ks & 3) * 16384;
    const char* lB = lA + 8192;
    __builtin_amdgcn_s_setprio(1);
#pragma unroll
    for (int ks2 = 0; ks2 < 2; ++ks2) {
      const int eo = (ks2 * 64 + q * 16) ^ swzr;
      const bf16x8 bf = *reinterpret_cast<const bf16x8*>(lB + col * 128 + eo);
#pragma unroll
      for (int mb = 0; mb < 4; ++mb) {
        const bf16x8 af = *reinterpret_cast<const bf16x8*>(lA + (mb * 16 + ln) * 128 + eo);
        acc[mb] = __builtin_amdgcn_mfma_f32_16x16x32_bf16(af, bf, acc[mb], 0, 0, 0);
      }
    }
    __builtin_amdgcn_s_setprio(0);
    __builtin_amdgcn_sched_barrier(0);
  }
  // exits with vm outstanding = 0; step-(NKS-1) barrier already passed.
}

// ---------------------------------------------------------------------------
// Fused phase p (p = 0..128), two independent concurrent sub-kernels
// (R6 winning schedule: merged K=2048 s3, no Gs partials):
//   blocks   0..255: fb(t=p)   — layer1/2 fwd+bwd step, K=768, writes comb[t+1]
//   blocks 256..511: s3(s=p-1) — FULL K=2048 layer-3 step (comb_s | h_{s-1})
//                                @ Wps^T + cell update -> hs[(s+1)&1]
// s3(s) inputs: comb slot s+1=p (fb phase p-1), hs slot s&1 (s3 phase p-1).
// XCD-pinned n-panels (bi&7 = XCD) dedup weight fetches within a phase.
// ---------------------------------------------------------------------------
__global__ __launch_bounds__(256, 2) void phase(int p,
    const unsigned short* __restrict__ xb,
    const unsigned short* __restrict__ Wpf, const unsigned short* __restrict__ Wpb,
    const float* __restrict__ bpf, const float* __restrict__ bpb,
    unsigned short* __restrict__ comb, float* __restrict__ cf, float* __restrict__ cb,
    const unsigned short* __restrict__ Wps, const float* __restrict__ bps,
    unsigned short* __restrict__ hs, float* __restrict__ cs) {
  __shared__ __align__(16) char sm[65536];
  const int bi = blockIdx.x;
  const int tid = threadIdx.x;
  const int w = tid >> 6;
  const int lane = tid & 63;
  const int q = lane >> 4;
  const int ln = lane & 15;
  const int col = w * 16 + ln;
  float* scratch = (float*)sm;   // 64x68 f32 epilogue scratch (17.4 KB), reused after K-loop

  if (bi < 256) {
    // ---------------- layer 1/2 step, t = p ----------------
    const int t = p;
    if (t >= TT) return;
    const int xcd = bi & 7;
    const int idx = bi >> 3;          // 0..31
    const int m0 = (idx & 3) * 64;
    const int slot = idx >> 2;        // 0..7
    const int panel = xcd * 8 + slot; // 0..63
    const int dir = panel & 1;
    const int n0 = (panel >> 1) * 64;
    const unsigned short* __restrict__ W = dir ? Wpb : Wpf;
    const float* __restrict__ bias = dir ? bpb : bpf;
    float* __restrict__ cbuf = dir ? cb : cf;
    const int dofs = dir ? HH : 0;
    const int tx = dir ? (TT - 1 - t) : t;

    f32x4 acc[4];
#pragma unroll
    for (int mb = 0; mb < 4; ++mb) acc[mb] = (f32x4){0.f, 0.f, 0.f, 0.f};
    gemm_tile_lds<768 / 64, DD>(
        xb + ((long)tx * BB + m0) * DD, DD,
        comb + ((long)t * BB + m0) * 1024 + dofs, 1024,
        W + (long)n0 * 768, 768, sm, tid, acc);

#pragma unroll
    for (int mb = 0; mb < 4; ++mb)
#pragma unroll
      for (int r = 0; r < 4; ++r)
        scratch[(mb * 16 + q * 4 + r) * 68 + col] = acc[mb][r];
    __syncthreads();

#pragma unroll
    for (int r = 0; r < 4; ++r) {
      const int cid = tid + r * 256;
      const int bl = cid >> 4;           // 0..63
      const int jl = cid & 15;           // 0..15
      const int b = m0 + bl;
      const int j = (n0 >> 2) + jl;      // 0..511
      const f32x4 g  = *reinterpret_cast<const f32x4*>(&scratch[bl * 68 + jl * 4]);
      const f32x4 bv = *reinterpret_cast<const f32x4*>(&bias[n0 + jl * 4]);
      const float gi = g[0] + bv[0];
      const float gf = g[1] + bv[1];
      const float gg = g[2] + bv[2];
      const float go = g[3] + bv[3];
      const float c_old = cbuf[(size_t)b * HH + j];
      const float c_new = sigm(gf) * c_old + sigm(gi) * tanh_f(gg);
      const float h = sigm(go) * tanh_f(c_new);
      cbuf[(size_t)b * HH + j] = c_new;
      comb[((size_t)(t + 1) * BB + b) * 1024 + dofs + j] = f2bf(h);
    }
  } else {
    // ---------------- layer 3 full step, s = p-1 ----------------
    if (p < 1) return;
    const int s = p - 1;
    const int bb2 = bi - 256;
    const int xcd = bb2 & 7;
    const int idx = bb2 >> 3;                     // 0..31
    const int m0 = (idx & 3) * 64;
    const int n0 = (xcd * 8 + (idx >> 2)) * 64;   // pinned panel 0..63 -> n0 0..4032

    f32x4 acc[4];
#pragma unroll
    for (int mb = 0; mb < 4; ++mb) acc[mb] = (f32x4){0.f, 0.f, 0.f, 0.f};
    gemm_tile_lds<2048 / 64, 1024>(
        comb + ((long)p * BB + m0) * 1024, 1024,          // combined[s] = slot p
        hs + ((long)(s & 1) * BB + m0) * 1024, 1024,      // h_{s-1}
        Wps + (long)n0 * 2048, 2048, sm, tid, acc);

#pragma unroll
    for (int mb = 0; mb < 4; ++mb)
#pragma unroll
      for (int r = 0; r < 4; ++r)
        scratch[(mb * 16 + q * 4 + r) * 68 + col] = acc[mb][r];
    __syncthreads();

#pragma unroll
    for (int r = 0; r < 4; ++r) {
      const int cid = tid + r * 256;
      const int bl = cid >> 4;
      const int jl = cid & 15;
      const int b = m0 + bl;
      const int j = (n0 >> 2) + jl;      // 0..1023
      const f32x4 g  = *reinterpret_cast<const f32x4*>(&scratch[bl * 68 + jl * 4]);
      const f32x4 bv = *reinterpret_cast<const f32x4*>(&bps[n0 + jl * 4]);
      const float gi = g[0] + bv[0];
      const float gf = g[1] + bv[1];
      const float gg = g[2] + bv[2];
      const float go = g[3] + bv[3];
      const float c_old = cs[(size_t)b * 1024 + j];
      const float c_new = sigm(gf) * c_old + sigm(gi) * tanh_f(gg);
      const float h = sigm(go) * tanh_f(c_new);
      cs[(size_t)b * 1024 + j] = c_new;
      hs[((size_t)((s + 1) & 1) * BB + b) * 1024 + j] = f2bf(h);
    }
  }
}

// ---------------------------------------------------------------------------
// out[b][l] = sigmoid(h_final[b] . Wl[l] + bl[l]);  h_final = hs slot (T&1)=0
// ---------------------------------------------------------------------------
__global__ __launch_bounds__(256) void classifier(const unsigned short* __restrict__ hs,
                                                  const float* __restrict__ Wl,
                                                  const float* __restrict__ bl,
                                                  float* __restrict__ out) {
  const int b = blockIdx.x;
  const int tid = threadIdx.x;
  const unsigned short* hb = hs + (size_t)b * 1024;  // slot 0 (T even)
  float s0 = 0.f, s1 = 0.f;
#pragma unroll
  for (int kk = 0; kk < 4; ++kk) {
    const int k = tid * 4 + kk;
    const float hv = bf2f(hb[k]);
    s0 += hv * Wl[k];
    s1 += hv * Wl[1024 + k];
  }
  for (int off = 32; off > 0; off >>= 1) {
    s0 += __shfl_down(s0, off);
    s1 += __shfl_down(s1, off);
  }
  __shared__ float red[8];
  const int w = tid >> 6;
  if ((tid & 63) == 0) { red[w * 2] = s0; red[w * 2 + 1] = s1; }
  __syncthreads();
  if (tid == 0) {
    const float l0 = red[0] + red[2] + red[4] + red[6] + bl[0];
    const float l1 = red[1] + red[3] + red[5] + red[7] + bl[1];
    out[b * 2 + 0] = sigm(l0);
    out[b * 2 + 1] = sigm(l1);
  }
}

// ---------------------------------------------------------------------------
extern "C" void kernel_launch(void* const* d_in, const int* in_sizes, int n_in,
                              void* d_out, int out_size, void* d_ws, size_t ws_size,
                              hipStream_t stream) {
  const float* x     = (const float*)d_in[0];
  const float* Wf_ih = (const float*)d_in[1];
  const float* Wf_hh = (const float*)d_in[2];
  const float* bf_   = (const float*)d_in[3];
  const float* Wb_ih = (const float*)d_in[4];
  const float* Wb_hh = (const float*)d_in[5];
  const float* bb_   = (const float*)d_in[6];
  const float* Ws_ih = (const float*)d_in[7];
  const float* Ws_hh = (const float*)d_in[8];
  const float* bs_   = (const float*)d_in[9];
  const float* Wl    = (const float*)d_in[10];
  const float* bl    = (const float*)d_in[11];
  float* out = (float*)d_out;

  char* ws = (char*)d_ws;
  size_t off = 0;
  auto take = [&](size_t bytes) -> void* {
    void* p = ws + off;
    off += (bytes + 255) & ~(size_t)255;
    return p;
  };
  unsigned short* xb   = (unsigned short*)take((size_t)BB * TT * DD * 2);       // 16 MB
  unsigned short* Wpf  = (unsigned short*)take((size_t)2048 * 768 * 2);         // 3 MB
  unsigned short* Wpb  = (unsigned short*)take((size_t)2048 * 768 * 2);         // 3 MB
  unsigned short* Wps  = (unsigned short*)take((size_t)4096 * 2048 * 2);        // 16 MB
  float* bpf = (float*)take(2048 * 4);
  float* bpb = (float*)take(2048 * 4);
  float* bps = (float*)take(4096 * 4);
  unsigned short* comb = (unsigned short*)take((size_t)(TT + 1) * BB * 1024 * 2); // 67.6 MB
  unsigned short* hs   = (unsigned short*)take((size_t)2 * BB * 1024 * 2);      // 1 MB
  float* cf = (float*)take((size_t)BB * HH * 4);
  float* cb = (float*)take((size_t)BB * HH * 4);
  float* cs = (float*)take((size_t)BB * 1024 * 4);
  // total ~111 MB

  prep<<<2048, 256, 0, stream>>>(x, Wf_ih, Wf_hh, bf_, Wb_ih, Wb_hh, bb_,
                                 Ws_ih, Ws_hh, bs_, xb, Wpf, Wpb, Wps,
                                 bpf, bpb, bps, comb, hs, cf, cb, cs);
  for (int p = 0; p <= TT; ++p)
    phase<<<512, 256, 0, stream>>>(p, xb, Wpf, Wpb, bpf, bpb, comb, cf, cb,
                                   Wps, bps, hs, cs);
  classifier<<<256, 256, 0, stream>>>(hs, Wl, bl, out);
}

// Round 12
// 1679.127 us; speedup vs baseline: 1.4461x; 1.1709x over previous
//
#include <hip/hip_runtime.h>
#include <math.h>

// Problem constants
#define BB 256   // batch
#define TT 128   // seq len
#define DD 256   // input dim
#define HH 512   // hidden (LSTM 1/2); LSTM 3 hidden = 2*HH = 1024

typedef __bf16 bf16x8 __attribute__((ext_vector_type(8)));
typedef float  f32x4  __attribute__((ext_vector_type(4)));

__device__ inline unsigned short f2bf(float f) {
  unsigned u = __builtin_bit_cast(unsigned, f);
  unsigned r = (u + 0x7fffu + ((u >> 16) & 1u)) >> 16;  // RNE
  return (unsigned short)r;
}
__device__ inline float bf2f(unsigned short h) {
  unsigned u = ((unsigned)h) << 16;
  return __builtin_bit_cast(float, u);
}
__device__ inline float sigm(float x)   { return 1.f / (1.f + __expf(-x)); }
__device__ inline float tanh_f(float x) { return 2.f / (1.f + __expf(-2.f * x)) - 1.f; }

// async global->LDS, 16 bytes per lane. lds ptr must be wave-uniform;
// HW writes at lds + lane*16 (guide §5). Global ptr is per-lane.
__device__ __forceinline__ void gl16(const void* g, void* l) {
  __builtin_amdgcn_global_load_lds(
      (const __attribute__((address_space(1))) unsigned int*)g,
      (__attribute__((address_space(3))) unsigned int*)l, 16, 0, 0);
}

// counted waits on the wave's own outstanding global_load_lds ops
__device__ __forceinline__ void vmw8() { asm volatile("s_waitcnt vmcnt(8)" ::: "memory"); }
__device__ __forceinline__ void vmw4() { asm volatile("s_waitcnt vmcnt(4)" ::: "memory"); }
__device__ __forceinline__ void vmw0() { asm volatile("s_waitcnt vmcnt(0)" ::: "memory"); }

// ---------------------------------------------------------------------------
// Prep: convert/pack everything to bf16, gate-interleaved weight layout.
// Packed weight row n = j*4 + g  (g: 0=i,1=f,2=g,3=o), K = [ih | hh] concat.
// xb transposed to [T][B][D] so a step's A-tile is contiguous.
// Zeroes comb slot 0, hs slots, and all c states (ws is poisoned each call).
// ---------------------------------------------------------------------------
__global__ void prep(const float* __restrict__ x,
                     const float* __restrict__ Wf_ih, const float* __restrict__ Wf_hh, const float* __restrict__ bf_,
                     const float* __restrict__ Wb_ih, const float* __restrict__ Wb_hh, const float* __restrict__ bb_,
                     const float* __restrict__ Ws_ih, const float* __restrict__ Ws_hh, const float* __restrict__ bs_,
                     unsigned short* __restrict__ xb, unsigned short* __restrict__ Wpf,
                     unsigned short* __restrict__ Wpb, unsigned short* __restrict__ Wps,
                     float* __restrict__ bpf, float* __restrict__ bpb, float* __restrict__ bps,
                     unsigned short* __restrict__ comb, unsigned short* __restrict__ hs,
                     float* __restrict__ cf, float* __restrict__ cb, float* __restrict__ cs) {
  const long gid = (long)blockIdx.x * blockDim.x + threadIdx.x;
  const long stride = (long)gridDim.x * blockDim.x;

  // x [B][T][D] -> xb [T][B][D] (bf16)
  for (long i = gid; i < (long)BB * TT * DD; i += stride) {
    long k = i % DD;
    long bt = i / DD;
    long t = bt % TT;
    long b = bt / TT;
    xb[(t * BB + b) * DD + k] = f2bf(x[i]);
  }
  // fwd/bwd packed weights: [2048][768]
  for (long i = gid; i < 2048L * 768; i += stride) {
    int n = (int)(i / 768), k = (int)(i - (long)n * 768);
    int j = n >> 2, g = n & 3;
    float vf = (k < DD) ? Wf_ih[(size_t)(g * HH + j) * DD + k]
                        : Wf_hh[(size_t)(g * HH + j) * HH + (k - DD)];
    float vb = (k < DD) ? Wb_ih[(size_t)(g * HH + j) * DD + k]
                        : Wb_hh[(size_t)(g * HH + j) * HH + (k - DD)];
    Wpf[i] = f2bf(vf);
    Wpb[i] = f2bf(vb);
  }
  // layer-3 packed weights: [4096][2048]
  for (long i = gid; i < 4096L * 2048; i += stride) {
    int n = (int)(i >> 11), k = (int)(i & 2047);
    int j = n >> 2, g = n & 3;
    float v = (k < 1024) ? Ws_ih[(size_t)(g * 1024 + j) * 1024 + k]
                         : Ws_hh[(size_t)(g * 1024 + j) * 1024 + (k - 1024)];
    Wps[i] = f2bf(v);
  }
  // biases (fp32, gate-interleaved)
  for (long i = gid; i < 2048; i += stride) {
    int j = (int)(i >> 2), g = (int)(i & 3);
    bpf[i] = bf_[g * HH + j];
    bpb[i] = bb_[g * HH + j];
  }
  for (long i = gid; i < 4096; i += stride) {
    int j = (int)(i >> 2), g = (int)(i & 3);
    bps[i] = bs_[g * 1024 + j];
  }
  // zero init: comb slot 0 (h_{-1} = 0), hs (both slots), c states
  for (long i = gid; i < (long)BB * 1024; i += stride) comb[i] = 0;
  for (long i = gid; i < 2L * BB * 1024; i += stride) hs[i] = 0;
  for (long i = gid; i < (long)BB * HH; i += stride) { cf[i] = 0.f; cb[i] = 0.f; }
  for (long i = gid; i < (long)BB * 1024; i += stride) cs[i] = 0.f;
}

// ---------------------------------------------------------------------------
// 64x64-tile GEMM, global_load_lds 3-buffer pipeline, BK=64, counted vmcnt.
// (R6 schedule — proven 1751 us — with 2x2 wave ownership: each wave owns a
// 32x32 quadrant (2 m-frags x 2 n-frags), so per 4 MFMA it reads 2 A + 2 B
// frags instead of 4 A + 1 B: LDS read traffic -20% (R11 post-mortem: only
// remaining lever that doesn't touch the verified schedule).)
//
// Per K-step: [vmcnt(counted); s_barrier]  (tile ks landed, never drain-0)
//             ds_read + MFMA on buf[ks%3]
//             [s_barrier]                  (all waves done reading)
//             stage(buf[ks%3], ks+3)       (WAR-safe overwrite)
// vmcnt counts the wave's own gload_lds instrs: 4 per stage per wave.
//
// LDS per buffer: A tile [64 rows][64 k] bf16 (8 KB) then B tile [64][64]
// (8 KB). Row stride 128 B. XOR swizzle: LDS byte (row*128 + e) holds
// global k-byte (e ^ ((row&7)<<4)) — applied on the SOURCE address at
// staging (gload_lds writes linearly) and on the ds_read address. Both new
// row maps keep row&7 = ln&7, so the swizzle read term is unchanged.
//
// A rows from aseg0 (k < KSPLIT) then aseg1 (k >= KSPLIT), 64-aligned.
// Frag: A[m=lane&15][k=(lane>>4)*8+j]; B likewise; C/D col=lane&15,
// row=(lane>>4)*4+reg. Wave w: wm=w>>1, wn=w&1; quadrant rows wm*32+mb*16,
// cols wn*32+nf*16.
// ---------------------------------------------------------------------------
template<int NKS, int KSPLIT>
__device__ __forceinline__ void gemm_tile_lds(
    const unsigned short* __restrict__ a0, long as0,   // A segment 0 (at row m0)
    const unsigned short* __restrict__ a1, long as1,   // A segment 1
    const unsigned short* __restrict__ wb, long ws,    // weight rows (at col n0)
    char* sm, int tid, f32x4 (&acc)[2][2]) {
  const int rl   = tid >> 3;              // staging row within 32-row half
  const int eb   = (tid & 7) * 16;        // staging byte-in-row
  const int kel  = (eb ^ ((rl & 7) << 4)) >> 1;   // pre-swizzled element offset
  const int wuni = (tid >> 6) * 1024;     // wave-uniform LDS sub-base

  const int lane = tid & 63;
  const int w    = tid >> 6;
  const int wm   = w >> 1;                // 0..1: m 32-half
  const int wn   = w & 1;                 // 0..1: n 32-half
  const int ln   = lane & 15;
  const int q    = lane >> 4;
  const int swzr = (ln & 7) << 4;

  auto stage = [&](int buf, int k0) {
    char* lA = sm + buf * 16384;
    char* lB = lA + 8192;
    const unsigned short* ab = (k0 < KSPLIT) ? (a0 + k0) : (a1 + (k0 - KSPLIT));
    const long astr = (k0 < KSPLIT) ? as0 : as1;
#pragma unroll
    for (int h = 0; h < 2; ++h) {
      const int row = h * 32 + rl;
      gl16(ab + (long)row * astr + kel, lA + h * 4096 + wuni);
      gl16(wb + (long)row * ws + k0 + kel, lB + h * 4096 + wuni);
    }
  };

  stage(0, 0); stage(1, 64); stage(2, 128);   // NKS >= 3 always

#pragma unroll 3
  for (int ks = 0; ks < NKS; ++ks) {
    if (ks < NKS - 2)       vmw8();   // tile ks landed; 2 tiles still in flight
    else if (ks == NKS - 2) vmw4();
    else                    vmw0();
    __builtin_amdgcn_sched_barrier(0);
    __builtin_amdgcn_s_barrier();               // all waves: tile ks complete
    __builtin_amdgcn_sched_barrier(0);
    const char* lA = sm + (ks % 3) * 16384;
    const char* lB = lA + 8192;
#pragma unroll
    for (int ks2 = 0; ks2 < 2; ++ks2) {
      const int eo = (ks2 * 64 + q * 16) ^ swzr;
      bf16x8 af[2], bf[2];
#pragma unroll
      for (int mb = 0; mb < 2; ++mb)
        af[mb] = *reinterpret_cast<const bf16x8*>(lA + (wm * 32 + mb * 16 + ln) * 128 + eo);
#pragma unroll
      for (int nf = 0; nf < 2; ++nf)
        bf[nf] = *reinterpret_cast<const bf16x8*>(lB + (wn * 32 + nf * 16 + ln) * 128 + eo);
#pragma unroll
      for (int mb = 0; mb < 2; ++mb)
#pragma unroll
        for (int nf = 0; nf < 2; ++nf)
          acc[mb][nf] = __builtin_amdgcn_mfma_f32_16x16x32_bf16(af[mb], bf[nf], acc[mb][nf], 0, 0, 0);
    }
    __builtin_amdgcn_sched_barrier(0);
    __builtin_amdgcn_s_barrier();               // all waves done reading buf[ks%3]
    __builtin_amdgcn_sched_barrier(0);
    if (ks + 3 < NKS) stage(ks % 3, (ks + 3) * 64);
  }
  // exits with vm outstanding = 0 and all waves past final barrier.
}

// ---------------------------------------------------------------------------
// Fused phase p (p = 0..128), two independent concurrent sub-kernels
// (R6 winning schedule: merged K=2048 s3, no Gs partials):
//   blocks   0..255: fb(t=p)   — layer1/2 fwd+bwd step, K=768, writes comb[t+1]
//   blocks 256..511: s3(s=p-1) — FULL K=2048 layer-3 step (comb_s | h_{s-1})
//                                @ Wps^T + cell update -> hs[(s+1)&1]
// s3(s) inputs: comb slot s+1=p (fb phase p-1), hs slot s&1 (s3 phase p-1).
// XCD-pinned n-panels (bi&7 = XCD) dedup weight fetches within a phase.
// ---------------------------------------------------------------------------
__global__ __launch_bounds__(256, 2) void phase(int p,
    const unsigned short* __restrict__ xb,
    const unsigned short* __restrict__ Wpf, const unsigned short* __restrict__ Wpb,
    const float* __restrict__ bpf, const float* __restrict__ bpb,
    unsigned short* __restrict__ comb, float* __restrict__ cf, float* __restrict__ cb,
    const unsigned short* __restrict__ Wps, const float* __restrict__ bps,
    unsigned short* __restrict__ hs, float* __restrict__ cs) {
  __shared__ __align__(16) char sm[49152];
  const int bi = blockIdx.x;
  const int tid = threadIdx.x;
  const int w = tid >> 6;
  const int lane = tid & 63;
  const int q = lane >> 4;
  const int ln = lane & 15;
  const int wm = w >> 1;
  const int wn = w & 1;
  float* scratch = (float*)sm;   // 64x68 f32 epilogue scratch (17.4 KB), reused after K-loop

  if (bi < 256) {
    // ---------------- layer 1/2 step, t = p ----------------
    const int t = p;
    if (t >= TT) return;
    const int xcd = bi & 7;
    const int idx = bi >> 3;          // 0..31
    const int m0 = (idx & 3) * 64;
    const int slot = idx >> 2;        // 0..7
    const int panel = xcd * 8 + slot; // 0..63
    const int dir = panel & 1;
    const int n0 = (panel >> 1) * 64;
    const unsigned short* __restrict__ W = dir ? Wpb : Wpf;
    const float* __restrict__ bias = dir ? bpb : bpf;
    float* __restrict__ cbuf = dir ? cb : cf;
    const int dofs = dir ? HH : 0;
    const int tx = dir ? (TT - 1 - t) : t;

    f32x4 acc[2][2];
#pragma unroll
    for (int mb = 0; mb < 2; ++mb)
#pragma unroll
      for (int nf = 0; nf < 2; ++nf) acc[mb][nf] = (f32x4){0.f, 0.f, 0.f, 0.f};
    gemm_tile_lds<768 / 64, DD>(
        xb + ((long)tx * BB + m0) * DD, DD,
        comb + ((long)t * BB + m0) * 1024 + dofs, 1024,
        W + (long)n0 * 768, 768, sm, tid, acc);

#pragma unroll
    for (int mb = 0; mb < 2; ++mb)
#pragma unroll
      for (int nf = 0; nf < 2; ++nf)
#pragma unroll
        for (int r = 0; r < 4; ++r)
          scratch[(wm * 32 + mb * 16 + q * 4 + r) * 68 + wn * 32 + nf * 16 + ln] = acc[mb][nf][r];
    __syncthreads();

#pragma unroll
    for (int r = 0; r < 4; ++r) {
      const int cid = tid + r * 256;
      const int bl = cid >> 4;           // 0..63
      const int jl = cid & 15;           // 0..15
      const int b = m0 + bl;
      const int j = (n0 >> 2) + jl;      // 0..511
      const f32x4 g  = *reinterpret_cast<const f32x4*>(&scratch[bl * 68 + jl * 4]);
      const f32x4 bv = *reinterpret_cast<const f32x4*>(&bias[n0 + jl * 4]);
      const float gi = g[0] + bv[0];
      const float gf = g[1] + bv[1];
      const float gg = g[2] + bv[2];
      const float go = g[3] + bv[3];
      const float c_old = cbuf[(size_t)b * HH + j];
      const float c_new = sigm(gf) * c_old + sigm(gi) * tanh_f(gg);
      const float h = sigm(go) * tanh_f(c_new);
      cbuf[(size_t)b * HH + j] = c_new;
      comb[((size_t)(t + 1) * BB + b) * 1024 + dofs + j] = f2bf(h);
    }
  } else {
    // ---------------- layer 3 full step, s = p-1 ----------------
    if (p < 1) return;
    const int s = p - 1;
    const int bb2 = bi - 256;
    const int xcd = bb2 & 7;
    const int idx = bb2 >> 3;                     // 0..31
    const int m0 = (idx & 3) * 64;
    const int n0 = (xcd * 8 + (idx >> 2)) * 64;   // pinned panel 0..63 -> n0 0..4032

    f32x4 acc[2][2];
#pragma unroll
    for (int mb = 0; mb < 2; ++mb)
#pragma unroll
      for (int nf = 0; nf < 2; ++nf) acc[mb][nf] = (f32x4){0.f, 0.f, 0.f, 0.f};
    gemm_tile_lds<2048 / 64, 1024>(
        comb + ((long)p * BB + m0) * 1024, 1024,          // combined[s] = slot p
        hs + ((long)(s & 1) * BB + m0) * 1024, 1024,      // h_{s-1}
        Wps + (long)n0 * 2048, 2048, sm, tid, acc);

#pragma unroll
    for (int mb = 0; mb < 2; ++mb)
#pragma unroll
      for (int nf = 0; nf < 2; ++nf)
#pragma unroll
        for (int r = 0; r < 4; ++r)
          scratch[(wm * 32 + mb * 16 + q * 4 + r) * 68 + wn * 32 + nf * 16 + ln] = acc[mb][nf][r];
    __syncthreads();

#pragma unroll
    for (int r = 0; r < 4; ++r) {
      const int cid = tid + r * 256;
      const int bl = cid >> 4;
      const int jl = cid & 15;
      const int b = m0 + bl;
      const int j = (n0 >> 2) + jl;      // 0..1023
      const f32x4 g  = *reinterpret_cast<const f32x4*>(&scratch[bl * 68 + jl * 4]);
      const f32x4 bv = *reinterpret_cast<const f32x4*>(&bps[n0 + jl * 4]);
      const float gi = g[0] + bv[0];
      const float gf = g[1] + bv[1];
      const float gg = g[2] + bv[2];
      const float go = g[3] + bv[3];
      const float c_old = cs[(size_t)b * 1024 + j];
      const float c_new = sigm(gf) * c_old + sigm(gi) * tanh_f(gg);
      const float h = sigm(go) * tanh_f(c_new);
      cs[(size_t)b * 1024 + j] = c_new;
      hs[((size_t)((s + 1) & 1) * BB + b) * 1024 + j] = f2bf(h);
    }
  }
}

// ---------------------------------------------------------------------------
// out[b][l] = sigmoid(h_final[b] . Wl[l] + bl[l]);  h_final = hs slot (T&1)=0
// ---------------------------------------------------------------------------
__global__ __launch_bounds__(256) void classifier(const unsigned short* __restrict__ hs,
                                                  const float* __restrict__ Wl,
                                                  const float* __restrict__ bl,
                                                  float* __restrict__ out) {
  const int b = blockIdx.x;
  const int tid = threadIdx.x;
  const unsigned short* hb = hs + (size_t)b * 1024;  // slot 0 (T even)
  float s0 = 0.f, s1 = 0.f;
#pragma unroll
  for (int kk = 0; kk < 4; ++kk) {
    const int k = tid * 4 + kk;
    const float hv = bf2f(hb[k]);
    s0 += hv * Wl[k];
    s1 += hv * Wl[1024 + k];
  }
  for (int off = 32; off > 0; off >>= 1) {
    s0 += __shfl_down(s0, off);
    s1 += __shfl_down(s1, off);
  }
  __shared__ float red[8];
  const int w = tid >> 6;
  if ((tid & 63) == 0) { red[w * 2] = s0; red[w * 2 + 1] = s1; }
  __syncthreads();
  if (tid == 0) {
    const float l0 = red[0] + red[2] + red[4] + red[6] + bl[0];
    const float l1 = red[1] + red[3] + red[5] + red[7] + bl[1];
    out[b * 2 + 0] = sigm(l0);
    out[b * 2 + 1] = sigm(l1);
  }
}

// ---------------------------------------------------------------------------
extern "C" void kernel_launch(void* const* d_in, const int* in_sizes, int n_in,
                              void* d_out, int out_size, void* d_ws, size_t ws_size,
                              hipStream_t stream) {
  const float* x     = (const float*)d_in[0];
  const float* Wf_ih = (const float*)d_in[1];
  const float* Wf_hh = (const float*)d_in[2];
  const float* bf_   = (const float*)d_in[3];
  const float* Wb_ih = (const float*)d_in[4];
  const float* Wb_hh = (const float*)d_in[5];
  const float* bb_   = (const float*)d_in[6];
  const float* Ws_ih = (const float*)d_in[7];
  const float* Ws_hh = (const float*)d_in[8];
  const float* bs_   = (const float*)d_in[9];
  const float* Wl    = (const float*)d_in[10];
  const float* bl    = (const float*)d_in[11];
  float* out = (float*)d_out;

  char* ws = (char*)d_ws;
  size_t off = 0;
  auto take = [&](size_t bytes) -> void* {
    void* p = ws + off;
    off += (bytes + 255) & ~(size_t)255;
    return p;
  };
  unsigned short* xb   = (unsigned short*)take((size_t)BB * TT * DD * 2);       // 16 MB
  unsigned short* Wpf  = (unsigned short*)take((size_t)2048 * 768 * 2);         // 3 MB
  unsigned short* Wpb  = (unsigned short*)take((size_t)2048 * 768 * 2);         // 3 MB
  unsigned short* Wps  = (unsigned short*)take((size_t)4096 * 2048 * 2);        // 16 MB
  float* bpf = (float*)take(2048 * 4);
  float* bpb = (float*)take(2048 * 4);
  float* bps = (float*)take(4096 * 4);
  unsigned short* comb = (unsigned short*)take((size_t)(TT + 1) * BB * 1024 * 2); // 67.6 MB
  unsigned short* hs   = (unsigned short*)take((size_t)2 * BB * 1024 * 2);      // 1 MB
  float* cf = (float*)take((size_t)BB * HH * 4);
  float* cb = (float*)take((size_t)BB * HH * 4);
  float* cs = (float*)take((size_t)BB * 1024 * 4);
  // total ~111 MB

  prep<<<2048, 256, 0, stream>>>(x, Wf_ih, Wf_hh, bf_, Wb_ih, Wb_hh, bb_,
                                 Ws_ih, Ws_hh, bs_, xb, Wpf, Wpb, Wps,
                                 bpf, bpb, bps, comb, hs, cf, cb, cs);
  for (int p = 0; p <= TT; ++p)
    phase<<<512, 256, 0, stream>>>(p, xb, Wpf, Wpb, bpf, bpb, comb, cf, cb,
                                   Wps, bps, hs, cs);
  classifier<<<256, 256, 0, stream>>>(hs, Wl, bl, out);
}